// Round 18
// baseline (699.814 us; speedup 1.0000x reference)
//
#include <hip/hip_runtime.h>
#include <hip/hip_bf16.h>

#define LYR 6
#define NH 12
#define DM 49
#define FFD 1024
#define NOUT 10
#define NB 8192
#define NWIN 168  // 16 KB windows: 6 layers * (6 pairs * 2 + 16 ff)
#define NG 2      // sample-pair groups per wave (2 samples each -> 4 samples/wave)

typedef __bf16 bf16x8 __attribute__((ext_vector_type(8)));
typedef float f32x4 __attribute__((ext_vector_type(4)));
typedef float f32x16 __attribute__((ext_vector_type(16)));
typedef unsigned int u32;
typedef u32 u32x4 __attribute__((ext_vector_type(4)));

static __device__ __forceinline__ f32x16 mfma32(u32x4 a, u32x4 b, f32x16 c) {
  return __builtin_amdgcn_mfma_f32_32x32x16_bf16(
      __builtin_bit_cast(bf16x8, a), __builtin_bit_cast(bf16x8, b), c, 0, 0, 0);
}

static __device__ __forceinline__ unsigned short f2bf(float f) {
  union { float f; unsigned u; } c; c.f = f;
  unsigned r = c.u + 0x7fffu + ((c.u >> 16) & 1u);
  return (unsigned short)(r >> 16);
}

static __device__ __forceinline__ u32 pk2(float a, float b) {
  __hip_bfloat162 h2 = __float22bfloat162_rn(make_float2(a, b));
  u32 r;
  __builtin_memcpy(&r, &h2, 4);
  return r;
}

static __device__ __forceinline__ void gload16(const void* gp, void* lp) {
  __builtin_amdgcn_global_load_lds(
      (const __attribute__((address_space(1))) unsigned int*)gp,
      (__attribute__((address_space(3))) unsigned int*)lp, 16, 0, 0);
}

// ===== 32x32x16 fragment-linear decode =====
// section = 4096 ushorts = [mt(2)][ks(4)][lane(64)][j(8)]
// col = 32*mt + (lane&31);  k = 16*ks + 4*(lane>>5) + (j&3) + 8*(j>>2)
static __device__ __forceinline__ void decode32(int idx, int& k, int& col) {
  int combo = idx >> 9;  // mt*4+ks
  int mt = combo >> 2, ks = combo & 3;
  int lane = (idx >> 3) & 63, j = idx & 7;
  col = 32 * mt + (lane & 31);
  k = 16 * ks + 4 * (lane >> 5) + (j & 3) + 8 * (j >> 2);
}

// blob layout: 168 x 16KB windows (same as r17). Per layer l (28 windows at l*28):
//   pair p: w=l*28+2p: [G_{2p}|G_{2p+1}]   w+1: [VC_{2p}|VC_{2p+1}]
//   ff chunk c: w = l*28+12+c: [W1F_c | W2F_c]

__global__ void prep_g_frag(const float* __restrict__ Wq, const float* __restrict__ bq,
                            const float* __restrict__ Wk, const float* __restrict__ bk,
                            unsigned short* __restrict__ blob) {
  const float QS = 1.44269504088896f / 7.0f;
  int lh = blockIdx.x, l = lh / NH, hd = lh % NH;
  unsigned short* base =
      blob + (size_t)(l * 28 + 2 * (hd >> 1)) * 8192 + (hd & 1) * 4096;
  for (int idx = threadIdx.x; idx < 4096; idx += blockDim.x) {
    int kk, cc;
    decode32(idx, kk, cc);
    float acc = 0.f;
    if (cc <= DM && kk <= DM) {
      for (int e = 0; e < DM; ++e) {
        float kv = (cc < DM) ? Wk[(size_t)lh * 2401 + cc * DM + e] : bk[lh * DM + e];
        float qv = (kk < DM) ? Wq[(size_t)lh * 2401 + kk * DM + e] : bq[lh * DM + e];
        acc += kv * qv;
      }
      acc *= QS;
    }
    base[idx] = f2bf(acc);
  }
}

__global__ void prep_comb_f32(const float* __restrict__ Wo, const float* __restrict__ bo,
                              const float* __restrict__ Wcat, const float* __restrict__ bcat,
                              float* __restrict__ C) {
  int lh = blockIdx.x, l = lh / NH, hh = lh % NH;
  float* base = C + (size_t)lh * 3200;  // [50][64]
  for (int idx = threadIdx.x; idx < 3200; idx += blockDim.x) {
    int e = idx >> 6, f = idx & 63;
    float val = 0.f;
    if (f < DM) {
      if (e < DM) {
        for (int c = 0; c < DM; ++c)
          val += Wo[(size_t)lh * 2401 + e * DM + c] *
                 Wcat[((size_t)l * 588 + hh * DM + c) * DM + f];
      } else {
        for (int c = 0; c < DM; ++c)
          val += bo[lh * DM + c] * Wcat[((size_t)l * 588 + hh * DM + c) * DM + f];
        if (hh == 0) val += bcat[l * DM + f];
      }
    }
    base[idx] = val;
  }
}

__global__ void prep_vc_frag(const float* __restrict__ Wv, const float* __restrict__ bv,
                             const float* __restrict__ C,
                             unsigned short* __restrict__ blob) {
  int lh = blockIdx.x, l = lh / NH, hd = lh % NH;
  const float* Cb = C + (size_t)lh * 3200;
  unsigned short* base =
      blob + (size_t)(l * 28 + 2 * (hd >> 1) + 1) * 8192 + (hd & 1) * 4096;
  for (int idx = threadIdx.x; idx < 4096; idx += blockDim.x) {
    int d, f;
    decode32(idx, d, f);
    float acc = 0.f;
    if (f < DM && d <= DM) {
      for (int e = 0; e < DM; ++e) {
        float wv = (d < DM) ? Wv[(size_t)lh * 2401 + d * DM + e] : bv[lh * DM + e];
        acc += wv * Cb[e * 64 + f];
      }
      if (d == DM) acc += Cb[DM * 64 + f];
    }
    base[idx] = f2bf(acc);
  }
}

__global__ void prep_ff_frag(const float* __restrict__ W1, const float* __restrict__ b1,
                             const float* __restrict__ W2,
                             unsigned short* __restrict__ blob) {
  int l = blockIdx.x >> 3, part = blockIdx.x & 7;
  for (int idx = part * 16384 + threadIdx.x; idx < (part + 1) * 16384; idx += blockDim.x) {
    int c = idx >> 13, within = idx & 8191, sec = within >> 12, sidx = within & 4095;
    unsigned short* dst =
        blob + (size_t)(l * 28 + 12 + c) * 8192 + sec * 4096;
    int d, col;
    decode32(sidx, d, col);
    float v = 0.f;
    if (sec == 0) {  // W1: cols j, k = d_aug
      int jcol = 64 * c + col;
      if (d < DM) v = W1[(size_t)l * DM * FFD + d * FFD + jcol];
      else if (d == DM) v = b1[l * FFD + jcol];
    } else {  // W2: cols f, k = j within chunk
      int jg = 64 * c + d;
      if (col < DM) v = W2[(size_t)l * FFD * DM + jg * DM + col];
    }
    dst[sidx] = f2bf(v);
  }
}

__global__ void prep_small(const float* __restrict__ g1, const float* __restrict__ b1,
                           const float* __restrict__ g2, const float* __restrict__ b2,
                           const float* __restrict__ bff2,
                           float* __restrict__ g1p, float* __restrict__ b1p,
                           float* __restrict__ g2p, float* __restrict__ b2p,
                           float* __restrict__ bff2p) {
  int idx = threadIdx.x;
  if (idx >= 384) return;
  int l = idx >> 6, d = idx & 63;
  bool v = d < DM;
  g1p[idx] = v ? g1[l * DM + d] : 0.f;
  b1p[idx] = v ? b1[l * DM + d] : 0.f;
  g2p[idx] = v ? g2[l * DM + d] : 0.f;
  b2p[idx] = v ? b2[l * DM + d] : 0.f;
  bff2p[idx] = v ? bff2[l * DM + d] : 0.f;
}

// ===== fused transformer: 32x32x16, 4 samples/wave, 2-wave blocks, 4 blocks/CU =====

// h tile layout (C of 32x32): col = lane&31 = t-global (2 samples x 16 tokens),
// row f = (r&3) + 8*(r>>2) + 4*(lane>>5) + 32*mt
static __device__ __forceinline__ void ln_pack32(const f32x16 (&ht)[2],
                                                 const float* gb, const float* bb,
                                                 int hp5, u32x4 (&xf)[4]) {
  float s = 0.f, s2 = 0.f;
#pragma unroll
  for (int mt = 0; mt < 2; ++mt)
#pragma unroll
    for (int r = 0; r < 16; ++r) { float v = ht[mt][r]; s += v; s2 += v * v; }
  s += __shfl_xor(s, 32, 64);
  s2 += __shfl_xor(s2, 32, 64);
  float mu = s * (1.f / 49.f);
  float rs = rsqrtf(s2 * (1.f / 49.f) - mu * mu + 1e-5f);
  float xn[2][16];
#pragma unroll
  for (int mt = 0; mt < 2; ++mt)
#pragma unroll
    for (int q = 0; q < 4; ++q) {
      f32x4 gq = *(const f32x4*)(gb + 32 * mt + 8 * q + 4 * hp5);
      f32x4 bq = *(const f32x4*)(bb + 32 * mt + 8 * q + 4 * hp5);
#pragma unroll
      for (int i = 0; i < 4; ++i)
        xn[mt][4 * q + i] = (ht[mt][4 * q + i] - mu) * rs * gq[i] + bq[i];
    }
  if (hp5 == 0) xn[1][9] = 1.0f;  // bias slot d=49 (mt=1, reg 9, half 0)
#pragma unroll
  for (int ks = 0; ks < 4; ++ks) {
    int mt = ks >> 1, rh = ks & 1;
#pragma unroll
    for (int w = 0; w < 4; ++w)
      xf[ks][w] = pk2(xn[mt][rh * 8 + 2 * w], xn[mt][rh * 8 + 2 * w + 1]);
  }
}

// softmax over s for this lane's token t; valid s live in regs 0-7 (t<16) or 8-15
static __device__ __forceinline__ void softmax32(const f32x16& sc, bool tl16,
                                                 u32x4& p0, u32x4& p1) {
  int base = tl16 ? 0 : 8;
  float e[8];
  float su = 0.f;
#pragma unroll
  for (int i = 0; i < 8; ++i) { e[i] = exp2f(sc[base + i]); su += e[i]; }
  su += __shfl_xor(su, 32, 64);
  float inv = 1.f / su;
  u32x4 v;
#pragma unroll
  for (int w = 0; w < 4; ++w) v[w] = pk2(e[2 * w] * inv, e[2 * w + 1] * inv);
  u32x4 z = {0u, 0u, 0u, 0u};
  p0 = tl16 ? v : z;
  p1 = tl16 ? z : v;
}

// 128 threads: window 16 KB -> 8 x 16B per thread
#define STAGE_LOAD(s)                                                         \
  do {                                                                        \
    const unsigned short* gsrc = blob + (size_t)(s) * 8192 + tid * 8;         \
    unsigned short* ldst = &wbuf[(s) & 1][wv * 512];                          \
    _Pragma("unroll") for (int r = 0; r < 8; ++r)                             \
        gload16(gsrc + r * 1024, ldst + r * 1024);                            \
  } while (0)

__global__ __launch_bounds__(128, 2) void transformer_kernel(
    const float* __restrict__ x, float* __restrict__ out,
    const unsigned short* __restrict__ blob,
    const float* __restrict__ lg1, const float* __restrict__ lb1,
    const float* __restrict__ lg2, const float* __restrict__ lb2,
    const float* __restrict__ b2p, const float* __restrict__ Wc,
    const float* __restrict__ bc) {
  __shared__ __align__(16) unsigned short wbuf[2][8192];
  const int tid = threadIdx.x;
  const int wv = tid >> 6, lane = tid & 63;
  const int t = lane & 31, hp5 = lane >> 5;
  const bool tl16 = (lane & 16) == 0;  // token < 16 (sample 0 of pair)
  const int s0 = blockIdx.x * 8 + wv * 4;
  const f32x16 z16 = {0.f, 0.f, 0.f, 0.f, 0.f, 0.f, 0.f, 0.f,
                      0.f, 0.f, 0.f, 0.f, 0.f, 0.f, 0.f, 0.f};

  STAGE_LOAD(0);

  // residual h: per group, 2 mtiles of C (rows f, cols t-global)
  f32x16 h[NG][2];
#pragma unroll
  for (int grp = 0; grp < NG; ++grp) {
    int smp = s0 + grp * 2 + (t >> 4);
    const float* xa = x + (size_t)smp * 784 + (t & 15) * DM;
#pragma unroll
    for (int mt = 0; mt < 2; ++mt)
#pragma unroll
      for (int r = 0; r < 16; ++r) {
        int f = (r & 3) + 8 * (r >> 2) + 4 * hp5 + 32 * mt;
        h[grp][mt][r] = (f < DM) ? xa[f] : 0.f;
      }
  }

  int w = 0;
  for (int layer = 0; layer < LYR; ++layer) {
    u32x4 xf[NG][4];
#pragma unroll
    for (int grp = 0; grp < NG; ++grp)
      ln_pack32(h[grp], lg1 + layer * 64, lb1 + layer * 64, hp5, xf[grp]);

    for (int hp = 0; hp < 6; ++hp) {
      // ---- window [G0|G1]: y = G@xn, scores = xn^T y, softmax -> pB ----
      __syncthreads();
      if (w + 1 < NWIN) STAGE_LOAD(w + 1);
      u32x4 pB[2][NG][2];
#pragma unroll
      for (int hh = 0; hh < 2; ++hh) {
        const u32x4* GW = (const u32x4*)(wbuf[w & 1] + hh * 4096);
        __builtin_amdgcn_s_setprio(1);
        f32x16 cy[NG][2];
#pragma unroll
        for (int grp = 0; grp < NG; ++grp) { cy[grp][0] = z16; cy[grp][1] = z16; }
#pragma unroll
        for (int mt = 0; mt < 2; ++mt)
#pragma unroll
          for (int ks = 0; ks < 4; ++ks) {
            u32x4 gw = GW[(mt * 4 + ks) * 64 + lane];
#pragma unroll
            for (int grp = 0; grp < NG; ++grp)
              cy[grp][mt] = mfma32(gw, xf[grp][ks], cy[grp][mt]);
          }
#pragma unroll
        for (int grp = 0; grp < NG; ++grp) {
          u32x4 yB[4];
#pragma unroll
          for (int ks = 0; ks < 4; ++ks) {
            int mt = ks >> 1, rh = ks & 1;
#pragma unroll
            for (int ww = 0; ww < 4; ++ww)
              yB[ks][ww] = pk2(cy[grp][mt][rh * 8 + 2 * ww],
                               cy[grp][mt][rh * 8 + 2 * ww + 1]);
          }
          f32x16 sc = z16;
#pragma unroll
          for (int ks = 0; ks < 4; ++ks) sc = mfma32(xf[grp][ks], yB[ks], sc);
          softmax32(sc, tl16, pB[hh][grp][0], pB[hh][grp][1]);
        }
        __builtin_amdgcn_s_setprio(0);
      }
      ++w;

      // ---- window [VC0|VC1]: u = xn @ Wvc ; h += u^T-chain @ p ----
      __syncthreads();
      if (w + 1 < NWIN) STAGE_LOAD(w + 1);
#pragma unroll
      for (int hh = 0; hh < 2; ++hh) {
        const u32x4* UW = (const u32x4*)(wbuf[w & 1] + hh * 4096);
        __builtin_amdgcn_s_setprio(1);
        f32x16 cu[NG][2];
#pragma unroll
        for (int grp = 0; grp < NG; ++grp) { cu[grp][0] = z16; cu[grp][1] = z16; }
#pragma unroll
        for (int nt = 0; nt < 2; ++nt)
#pragma unroll
          for (int ks = 0; ks < 4; ++ks) {
            u32x4 wu = UW[(nt * 4 + ks) * 64 + lane];
#pragma unroll
            for (int grp = 0; grp < NG; ++grp)
              cu[grp][nt] = mfma32(xf[grp][ks], wu, cu[grp][nt]);
          }
#pragma unroll
        for (int grp = 0; grp < NG; ++grp)
#pragma unroll
          for (int nt = 0; nt < 2; ++nt) {
#pragma unroll
            for (int kss = 0; kss < 2; ++kss) {
              u32x4 uB;
#pragma unroll
              for (int ww = 0; ww < 4; ++ww)
                uB[ww] = pk2(cu[grp][nt][kss * 8 + 2 * ww],
                             cu[grp][nt][kss * 8 + 2 * ww + 1]);
              h[grp][nt] = mfma32(uB, pB[hh][grp][kss], h[grp][nt]);
            }
          }
        __builtin_amdgcn_s_setprio(0);
      }
      ++w;
    }

    // LN2 then h += b2 (FF2 accumulates into the residual)
#pragma unroll
    for (int grp = 0; grp < NG; ++grp)
      ln_pack32(h[grp], lg2 + layer * 64, lb2 + layer * 64, hp5, xf[grp]);
#pragma unroll
    for (int mt = 0; mt < 2; ++mt)
#pragma unroll
      for (int q = 0; q < 4; ++q) {
        f32x4 bb = *(const f32x4*)(b2p + layer * 64 + 32 * mt + 8 * q + 4 * hp5);
#pragma unroll
        for (int grp = 0; grp < NG; ++grp)
#pragma unroll
          for (int i = 0; i < 4; ++i) h[grp][mt][4 * q + i] += bb[i];
      }

    for (int c = 0; c < 16; ++c) {
      // ---- ff window: [W1F_c | W2F_c] ----
      __syncthreads();
      if (w + 1 < NWIN) STAGE_LOAD(w + 1);
      const u32x4* W1c = (const u32x4*)wbuf[w & 1];
      const u32x4* W2c = (const u32x4*)(wbuf[w & 1] + 4096);
      __builtin_amdgcn_s_setprio(1);
      f32x16 ca[NG][2];
#pragma unroll
      for (int grp = 0; grp < NG; ++grp) { ca[grp][0] = z16; ca[grp][1] = z16; }
#pragma unroll
      for (int jt = 0; jt < 2; ++jt)
#pragma unroll
        for (int ks = 0; ks < 4; ++ks) {
          u32x4 w1 = W1c[(jt * 4 + ks) * 64 + lane];
#pragma unroll
          for (int grp = 0; grp < NG; ++grp)
            ca[grp][jt] = mfma32(w1, xf[grp][ks], ca[grp][jt]);
        }
      u32x4 aB[NG][4];
#pragma unroll
      for (int grp = 0; grp < NG; ++grp)
#pragma unroll
        for (int ks = 0; ks < 4; ++ks) {
          int jt = ks >> 1, rh = ks & 1;
#pragma unroll
          for (int ww = 0; ww < 4; ++ww)
            aB[grp][ks][ww] =
                pk2(fmaxf(ca[grp][jt][rh * 8 + 2 * ww], 0.f),
                    fmaxf(ca[grp][jt][rh * 8 + 2 * ww + 1], 0.f));
        }
#pragma unroll
      for (int ft = 0; ft < 2; ++ft)
#pragma unroll
        for (int ks = 0; ks < 4; ++ks) {
          u32x4 w2 = W2c[(ft * 4 + ks) * 64 + lane];
#pragma unroll
          for (int grp = 0; grp < NG; ++grp)
            h[grp][ft] = mfma32(w2, aB[grp][ks], h[grp][ft]);
        }
      __builtin_amdgcn_s_setprio(0);
      ++w;
    }
  }

  // ---- classification head on token 0 of each sample ----
  __syncthreads();
  float* hs = (float*)&wbuf[0][0];  // [2 waves][4 samples][64]
  if ((lane & 15) == 0) {
    int sw = (lane >> 4) & 1;  // sample-in-pair (t==0 or t==16)
#pragma unroll
    for (int grp = 0; grp < NG; ++grp) {
      int si = wv * 4 + grp * 2 + sw;
#pragma unroll
      for (int mt = 0; mt < 2; ++mt)
#pragma unroll
        for (int r = 0; r < 16; ++r) {
          int f = (r & 3) + 8 * (r >> 2) + 4 * hp5 + 32 * mt;
          hs[si * 64 + f] = h[grp][mt][r];
        }
    }
  }
  __syncthreads();
  if (lane < 40) {
    int smp = lane / 10, c = lane % 10;
    float acc = bc[c];
    const float* hrow = hs + (wv * 4 + smp) * 64;
    for (int d = 0; d < DM; ++d) acc += hrow[d] * Wc[d * NOUT + c];
    out[(size_t)(s0 + smp) * NOUT + c] = acc;
  }
}

extern "C" void kernel_launch(void* const* d_in, const int* in_sizes, int n_in,
                              void* d_out, int out_size, void* d_ws, size_t ws_size,
                              hipStream_t stream) {
  const float* x = (const float*)d_in[0];
  const float* Wq = (const float*)d_in[2];
  const float* bq = (const float*)d_in[3];
  const float* Wk = (const float*)d_in[4];
  const float* bk = (const float*)d_in[5];
  const float* Wv = (const float*)d_in[6];
  const float* bv = (const float*)d_in[7];
  const float* Wo = (const float*)d_in[8];
  const float* bo = (const float*)d_in[9];
  const float* Wcat = (const float*)d_in[10];
  const float* bcat = (const float*)d_in[11];
  const float* ln1_g = (const float*)d_in[12];
  const float* ln1_b = (const float*)d_in[13];
  const float* ln2_g = (const float*)d_in[14];
  const float* ln2_b = (const float*)d_in[15];
  const float* W1 = (const float*)d_in[16];
  const float* b1 = (const float*)d_in[17];
  const float* W2 = (const float*)d_in[18];
  const float* b2 = (const float*)d_in[19];
  const float* Wc = (const float*)d_in[20];
  const float* bc = (const float*)d_in[21];

  unsigned short* blob = (unsigned short*)d_ws;  // NWIN * 8192 ushorts
  float* Cscr = (float*)(blob + (size_t)NWIN * 8192);  // 72 * 3200 f32
  float* fp = Cscr + (size_t)72 * 3200;
  float* g1p = fp;
  float* b1p = g1p + 384;
  float* g2p = b1p + 384;
  float* b2lp = g2p + 384;
  float* b2p = b2lp + 384;

  prep_g_frag<<<72, 256, 0, stream>>>(Wq, bq, Wk, bk, blob);
  prep_comb_f32<<<72, 256, 0, stream>>>(Wo, bo, Wcat, bcat, Cscr);
  prep_vc_frag<<<72, 256, 0, stream>>>(Wv, bv, Cscr, blob);
  prep_ff_frag<<<48, 256, 0, stream>>>(W1, b1, W2, blob);
  prep_small<<<1, 384, 0, stream>>>(ln1_g, ln1_b, ln2_g, ln2_b, b2, g1p, b1p, g2p, b2lp, b2p);

  // 2 waves * 4 samples per block => 1024 blocks
  transformer_kernel<<<NB / 8, 128, 0, stream>>>(
      x, (float*)d_out, blob, g1p, b1p, g2p, b2lp, b2p, Wc, bc);
}

// Round 19
// 526.443 us; speedup vs baseline: 1.3293x; 1.3293x over previous
//
#include <hip/hip_runtime.h>
#include <hip/hip_bf16.h>

#define LYR 6
#define NH 12
#define DM 49
#define FFD 1024
#define NOUT 10
#define NB 8192
#define NWIN 168  // 16 KB windows: 6 layers * (6 pairs * 2 + 16 ff)
#define SPW 2     // samples per wave

typedef __bf16 bf16x8 __attribute__((ext_vector_type(8)));
typedef float f32x4 __attribute__((ext_vector_type(4)));
typedef unsigned int u32;
typedef u32 u32x4 __attribute__((ext_vector_type(4)));

static __device__ __forceinline__ f32x4 mfma_full(u32x4 a, u32x4 b, f32x4 c) {
  return __builtin_amdgcn_mfma_f32_16x16x32_bf16(
      __builtin_bit_cast(bf16x8, a), __builtin_bit_cast(bf16x8, b), c, 0, 0, 0);
}

static __device__ __forceinline__ f32x4 mfma_hz(u32 a0, u32 a1, u32 b0, u32 b1, f32x4 c) {
  u32x4 A = {a0, a1, 0u, 0u};
  u32x4 B = {b0, b1, 0u, 0u};
  return mfma_full(A, B, c);
}

static __device__ __forceinline__ unsigned short f2bf(float f) {
  union { float f; unsigned u; } c; c.f = f;
  unsigned r = c.u + 0x7fffu + ((c.u >> 16) & 1u);
  return (unsigned short)(r >> 16);
}

// packed f32x2 -> bf16x2 ; lowers to v_cvt_pk_bf16_f32 (RNE, same as f2bf)
static __device__ __forceinline__ u32 pk2(float a, float b) {
  __hip_bfloat162 h2 = __float22bfloat162_rn(make_float2(a, b));
  u32 r;
  __builtin_memcpy(&r, &h2, 4);
  return r;
}

// direct global->LDS copy, 16B per lane; lds dest must be wave-uniform base
static __device__ __forceinline__ void gload16(const void* gp, void* lp) {
  __builtin_amdgcn_global_load_lds(
      (const __attribute__((address_space(1))) unsigned int*)gp,
      (__attribute__((address_space(3))) unsigned int*)lp, 16, 0, 0);
}

// ============ fragment-linear section decode ============
// section = 4096 ushorts: idx = ((tile*2+ks)*64+lane)*8 + j
// col = 16*tile + (lane&15);  k-slot d = 16*(2*ks + (j>=4)) + 4*(lane>>4) + (j&3)
static __device__ __forceinline__ void decode(int idx, int& d, int& col) {
  int tile = idx >> 10, ks = (idx >> 9) & 1, lane = (idx >> 3) & 63, j = idx & 7;
  col = 16 * tile + (lane & 15);
  d = 16 * (2 * ks + (j >= 4 ? 1 : 0)) + 4 * (lane >> 4) + (j & 3);
}

// blob layout: 168 x 16KB windows. Per layer l (28 windows at l*28):
//   pair p (heads 2p, 2p+1): w=l*28+2p:   [G_{2p}  | G_{2p+1}]
//                            w=l*28+2p+1: [VC_{2p} | VC_{2p+1}]
//   ff chunk c: w = l*28 + 12 + c: [W1F_c | W2F_c]

// G = Wk_aug @ Wq_aug^T (scores = xn^T G xn), bias rows folded, QS folded.
__global__ void prep_g_frag(const float* __restrict__ Wq, const float* __restrict__ bq,
                            const float* __restrict__ Wk, const float* __restrict__ bk,
                            unsigned short* __restrict__ blob) {
  const float QS = 1.44269504088896f / 7.0f;  // log2e/sqrt(D): softmax uses exp2
  int lh = blockIdx.x, l = lh / NH, hd = lh % NH;
  unsigned short* base =
      blob + (size_t)(l * 28 + 2 * (hd >> 1)) * 8192 + (hd & 1) * 4096;
  for (int idx = threadIdx.x; idx < 4096; idx += blockDim.x) {
    int kk, cc;
    decode(idx, kk, cc);
    float acc = 0.f;
    if (cc <= DM && kk <= DM) {
      for (int e = 0; e < DM; ++e) {
        float kv = (cc < DM) ? Wk[(size_t)lh * 2401 + cc * DM + e] : bk[lh * DM + e];
        float qv = (kk < DM) ? Wq[(size_t)lh * 2401 + kk * DM + e] : bq[lh * DM + e];
        acc += kv * qv;
      }
      acc *= QS;
    }
    base[idx] = f2bf(acc);
  }
}

// Wcomb_aug (f32 scratch): C[lh][e][f], e in [0,49] (e=DM row = bias row), f in [0,64)
__global__ void prep_comb_f32(const float* __restrict__ Wo, const float* __restrict__ bo,
                              const float* __restrict__ Wcat, const float* __restrict__ bcat,
                              float* __restrict__ C) {
  int lh = blockIdx.x, l = lh / NH, hh = lh % NH;
  float* base = C + (size_t)lh * 3200;  // [50][64]
  for (int idx = threadIdx.x; idx < 3200; idx += blockDim.x) {
    int e = idx >> 6, f = idx & 63;
    float val = 0.f;
    if (f < DM) {
      if (e < DM) {
        for (int c = 0; c < DM; ++c)
          val += Wo[(size_t)lh * 2401 + e * DM + c] *
                 Wcat[((size_t)l * 588 + hh * DM + c) * DM + f];
      } else {  // e == DM: bias row from bo (+ bcat once, head 0)
        for (int c = 0; c < DM; ++c)
          val += bo[lh * DM + c] * Wcat[((size_t)l * 588 + hh * DM + c) * DM + f];
        if (hh == 0) val += bcat[l * DM + f];
      }
    }
    base[idx] = val;
  }
}

// W_vc = Wv_aug @ Wcomb[:DM]  (+ Wcomb bias row folded into d=DM, since sum(p)=1)
__global__ void prep_vc_frag(const float* __restrict__ Wv, const float* __restrict__ bv,
                             const float* __restrict__ C,
                             unsigned short* __restrict__ blob) {
  int lh = blockIdx.x, l = lh / NH, hd = lh % NH;
  const float* Cb = C + (size_t)lh * 3200;
  unsigned short* base =
      blob + (size_t)(l * 28 + 2 * (hd >> 1) + 1) * 8192 + (hd & 1) * 4096;
  for (int idx = threadIdx.x; idx < 4096; idx += blockDim.x) {
    int d, f;
    decode(idx, d, f);
    float acc = 0.f;
    if (f < DM && d <= DM) {
      for (int e = 0; e < DM; ++e) {
        float wv = (d < DM) ? Wv[(size_t)lh * 2401 + d * DM + e] : bv[lh * DM + e];
        acc += wv * Cb[e * 64 + f];
      }
      if (d == DM) acc += Cb[DM * 64 + f];  // comb bias row (softmax rows sum to 1)
    }
    base[idx] = f2bf(acc);
  }
}

__global__ void prep_ff_frag(const float* __restrict__ W1, const float* __restrict__ b1,
                             const float* __restrict__ W2,
                             unsigned short* __restrict__ blob) {
  int l = blockIdx.x >> 3, part = blockIdx.x & 7;
  for (int idx = part * 16384 + threadIdx.x; idx < (part + 1) * 16384; idx += blockDim.x) {
    int c = idx >> 13, within = idx & 8191, sec = within >> 12, sidx = within & 4095;
    unsigned short* dst =
        blob + (size_t)(l * 28 + 12 + c) * 8192 + sec * 4096;
    int d, col;
    decode(sidx, d, col);
    float v = 0.f;
    if (sec == 0) {  // W1: cols j, k = d_aug
      int jcol = 64 * c + col;
      if (d < DM) v = W1[(size_t)l * DM * FFD + d * FFD + jcol];
      else if (d == DM) v = b1[l * FFD + jcol];
    } else {  // W2: cols f, k = j within chunk
      int jg = 64 * c + d;
      if (col < DM) v = W2[(size_t)l * FFD * DM + jg * DM + col];
    }
    dst[sidx] = f2bf(v);
  }
}

__global__ void prep_small(const float* __restrict__ g1, const float* __restrict__ b1,
                           const float* __restrict__ g2, const float* __restrict__ b2,
                           const float* __restrict__ bff2,
                           float* __restrict__ g1p, float* __restrict__ b1p,
                           float* __restrict__ g2p, float* __restrict__ b2p,
                           float* __restrict__ bff2p) {
  int idx = threadIdx.x;
  if (idx >= 384) return;
  int l = idx >> 6, d = idx & 63;
  bool v = d < DM;
  g1p[idx] = v ? g1[l * DM + d] : 0.f;
  b1p[idx] = v ? b1[l * DM + d] : 0.f;
  g2p[idx] = v ? g2[l * DM + d] : 0.f;
  b2p[idx] = v ? b2[l * DM + d] : 0.f;
  bff2p[idx] = v ? bff2[l * DM + d] : 0.f;
}

// ===== fused transformer: SPW=2, 4-wave blocks, 4 blocks/CU, sc-carry (no spill) =====

static __device__ __forceinline__ void ln_pack(const f32x4 (&h)[4], const f32x4 (&gv)[4],
                                               const f32x4 (&bv)[4], int g, u32x4 (&xf)[2]) {
  float s = 0.f, s2 = 0.f;
#pragma unroll
  for (int mi = 0; mi < 4; ++mi)
#pragma unroll
    for (int r = 0; r < 4; ++r) { float v = h[mi][r]; s += v; s2 += v * v; }
  s += __shfl_xor(s, 16, 64); s += __shfl_xor(s, 32, 64);
  s2 += __shfl_xor(s2, 16, 64); s2 += __shfl_xor(s2, 32, 64);
  float mu = s * (1.f / 49.f);
  float rs = rsqrtf(s2 * (1.f / 49.f) - mu * mu + 1e-5f);
  u32 t[8];
#pragma unroll
  for (int mi = 0; mi < 4; ++mi) {
    float xv[4];
#pragma unroll
    for (int r = 0; r < 4; ++r) xv[r] = (h[mi][r] - mu) * rs * gv[mi][r] + bv[mi][r];
    if (mi == 3) xv[1] = (g == 0) ? 1.0f : xv[1];  // bias slot d=49 := 1
    t[2 * mi] = pk2(xv[0], xv[1]);
    t[2 * mi + 1] = pk2(xv[2], xv[3]);
  }
  xf[0] = u32x4{t[0], t[1], t[2], t[3]};
  xf[1] = u32x4{t[4], t[5], t[6], t[7]};
}

// scores are O(1) (0.02-std weights, LN'd acts); log2e pre-folded -> plain exp2
static __device__ __forceinline__ void softmax_pk(f32x4 s, u32& p0, u32& p1) {
  float e0 = exp2f(s[0]), e1 = exp2f(s[1]);
  float e2 = exp2f(s[2]), e3 = exp2f(s[3]);
  float su = e0 + e1 + e2 + e3;
  su += __shfl_xor(su, 16, 64);
  su += __shfl_xor(su, 32, 64);
  float inv = 1.f / su;
  p0 = pk2(e0 * inv, e1 * inv);
  p1 = pk2(e2 * inv, e3 * inv);
}

// issue next window's loads: per-lane global src, wave-uniform LDS dest + lane*16
// 4 waves x 4 instrs x 512 ushorts = 8192 ushort window
#define STAGE_LOAD(s)                                                         \
  do {                                                                        \
    const unsigned short* gsrc = blob + (size_t)(s) * 8192 + tid * 8;         \
    unsigned short* ldst = &wbuf[(s) & 1][wv * 512];                          \
    _Pragma("unroll") for (int r = 0; r < 4; ++r)                             \
        gload16(gsrc + r * 2048, ldst + r * 2048);                            \
  } while (0)

__global__ __launch_bounds__(256, 4) void transformer_kernel(
    const float* __restrict__ x, float* __restrict__ out,
    const unsigned short* __restrict__ blob,
    const float* __restrict__ lg1, const float* __restrict__ lb1,
    const float* __restrict__ lg2, const float* __restrict__ lb2,
    const float* __restrict__ b2p, const float* __restrict__ Wc,
    const float* __restrict__ bc) {
  __shared__ __align__(16) unsigned short wbuf[2][8192];
  const int tid = threadIdx.x;
  const int wv = tid >> 6, lane = tid & 63;
  const int g = lane >> 4, li = lane & 15;
  const int s0 = blockIdx.x * 8 + wv * 2;
  const f32x4 z4 = {0.f, 0.f, 0.f, 0.f};

  STAGE_LOAD(0);

  // h tiles: h[s][mi][r] = h[d=16mi+4g+r][t=li] for sample s0+s
  f32x4 h[SPW][4];
#pragma unroll
  for (int s = 0; s < SPW; ++s) {
    const float* xa = x + (size_t)(s0 + s) * 784 + li * DM;
#pragma unroll
    for (int mi = 0; mi < 4; ++mi)
#pragma unroll
      for (int r = 0; r < 4; ++r) {
        int d = 16 * mi + 4 * g + r;
        h[s][mi][r] = (d < DM) ? xa[d] : 0.f;
      }
  }

  int w = 0;
  for (int layer = 0; layer < LYR; ++layer) {
    u32x4 xf[SPW][2];
    {
      f32x4 gv[4], bv[4];
#pragma unroll
      for (int mi = 0; mi < 4; ++mi) {
        int off = layer * 64 + 16 * mi + 4 * g;
        gv[mi] = *(const f32x4*)(lg1 + off);
        bv[mi] = *(const f32x4*)(lb1 + off);
      }
#pragma unroll
      for (int s = 0; s < SPW; ++s) ln_pack(h[s], gv, bv, g, xf[s]);
    }

    for (int hp = 0; hp < 6; ++hp) {
      // ---- window [G0|G1]: y = G @ xn, scores (per head, sequential) ----
      __syncthreads();
      if (w + 1 < NWIN) STAGE_LOAD(w + 1);
      f32x4 sc[2][SPW];  // carried across the next barrier
#pragma unroll
      for (int hh = 0; hh < 2; ++hh) {
        const u32x4* GW = (const u32x4*)(wbuf[w & 1] + hh * 4096);
        __builtin_amdgcn_s_setprio(1);
        u32x4 yf[SPW][2];
#pragma unroll
        for (int mi = 0; mi < 4; ++mi) {
          f32x4 cy[SPW];
#pragma unroll
          for (int s = 0; s < SPW; ++s) cy[s] = z4;
#pragma unroll
          for (int ks = 0; ks < 2; ++ks) {
            u32x4 gw = GW[(mi * 2 + ks) * 64 + lane];
#pragma unroll
            for (int s = 0; s < SPW; ++s) cy[s] = mfma_full(gw, xf[s][ks], cy[s]);
          }
#pragma unroll
          for (int s = 0; s < SPW; ++s) {
            yf[s][mi >> 1][2 * (mi & 1)] = pk2(cy[s][0], cy[s][1]);
            yf[s][mi >> 1][2 * (mi & 1) + 1] = pk2(cy[s][2], cy[s][3]);
          }
        }
#pragma unroll
        for (int s = 0; s < SPW; ++s) {
          sc[hh][s] = mfma_full(xf[s][0], yf[s][0], z4);
          sc[hh][s] = mfma_full(xf[s][1], yf[s][1], sc[hh][s]);
        }
        __builtin_amdgcn_s_setprio(0);
      }
      ++w;

      // ---- window [VC0|VC1]: u = xn @ Wvc ; softmax (overlapped) ; h += p @ u ----
      __syncthreads();
      if (w + 1 < NWIN) STAGE_LOAD(w + 1);
#pragma unroll
      for (int hh = 0; hh < 2; ++hh) {
        const u32x4* UW = (const u32x4*)(wbuf[w & 1] + hh * 4096);
        __builtin_amdgcn_s_setprio(1);
        u32 uf[4][SPW][2];
#pragma unroll
        for (int nt = 0; nt < 4; ++nt) {
          f32x4 cu[SPW];
#pragma unroll
          for (int s = 0; s < SPW; ++s) cu[s] = z4;
#pragma unroll
          for (int ks = 0; ks < 2; ++ks) {
            u32x4 wu = UW[(nt * 2 + ks) * 64 + lane];
#pragma unroll
            for (int s = 0; s < SPW; ++s) cu[s] = mfma_full(xf[s][ks], wu, cu[s]);
          }
#pragma unroll
          for (int s = 0; s < SPW; ++s) {
            uf[nt][s][0] = pk2(cu[s][0], cu[s][1]);
            uf[nt][s][1] = pk2(cu[s][2], cu[s][3]);
          }
        }
        // softmax here: VALU chain independent of the u MFMAs above -> overlaps
        u32 p[SPW][2];
#pragma unroll
        for (int s = 0; s < SPW; ++s) softmax_pk(sc[hh][s], p[s][0], p[s][1]);
        // PV (K=16) directly into the residual h
#pragma unroll
        for (int nt = 0; nt < 4; ++nt)
#pragma unroll
          for (int s = 0; s < SPW; ++s)
            h[s][nt] = mfma_hz(uf[nt][s][0], uf[nt][s][1], p[s][0], p[s][1], h[s][nt]);
        __builtin_amdgcn_s_setprio(0);
      }
      ++w;
    }

    // LN2 on x2 (= h), then h += b2 so FF2 accumulates into the residual
    {
      f32x4 gv[4], bv[4];
#pragma unroll
      for (int mi = 0; mi < 4; ++mi) {
        int off = layer * 64 + 16 * mi + 4 * g;
        gv[mi] = *(const f32x4*)(lg2 + off);
        bv[mi] = *(const f32x4*)(lb2 + off);
      }
#pragma unroll
      for (int s = 0; s < SPW; ++s) ln_pack(h[s], gv, bv, g, xf[s]);
#pragma unroll
      for (int mi = 0; mi < 4; ++mi) {
        f32x4 bb = *(const f32x4*)(b2p + layer * 64 + 16 * mi + 4 * g);
#pragma unroll
        for (int s = 0; s < SPW; ++s) h[s][mi] += bb;
      }
    }

    for (int c = 0; c < 16; ++c) {
      // ---- ff window: [W1F_c | W2F_c] ----
      __syncthreads();
      if (w + 1 < NWIN) STAGE_LOAD(w + 1);
      const u32x4* W1c = (const u32x4*)wbuf[w & 1];
      const u32x4* W2c = (const u32x4*)(wbuf[w & 1] + 4096);
      __builtin_amdgcn_s_setprio(1);
      u32x4 af[SPW][2];
#pragma unroll
      for (int jt = 0; jt < 4; ++jt) {
        f32x4 ca[SPW];
#pragma unroll
        for (int s = 0; s < SPW; ++s) ca[s] = z4;
#pragma unroll
        for (int ks = 0; ks < 2; ++ks) {
          u32x4 ww = W1c[(jt * 2 + ks) * 64 + lane];
#pragma unroll
          for (int s = 0; s < SPW; ++s) ca[s] = mfma_full(ww, xf[s][ks], ca[s]);
        }
#pragma unroll
        for (int s = 0; s < SPW; ++s) {
          float r0 = fmaxf(ca[s][0], 0.f), r1 = fmaxf(ca[s][1], 0.f);
          float r2 = fmaxf(ca[s][2], 0.f), r3 = fmaxf(ca[s][3], 0.f);
          af[s][jt >> 1][2 * (jt & 1)] = pk2(r0, r1);
          af[s][jt >> 1][2 * (jt & 1) + 1] = pk2(r2, r3);
        }
      }
#pragma unroll
      for (int ft = 0; ft < 4; ++ft) {
#pragma unroll
        for (int ks = 0; ks < 2; ++ks) {
          u32x4 ww = W2c[(ft * 2 + ks) * 64 + lane];
#pragma unroll
          for (int s = 0; s < SPW; ++s) h[s][ft] = mfma_full(ww, af[s][ks], h[s][ft]);
        }
      }
      __builtin_amdgcn_s_setprio(0);
      ++w;
    }
  }

  // ---- classification head on token 0 (col li==0); overlay scratch on wbuf ----
  __syncthreads();
  float* hs = (float*)&wbuf[0][0];  // [4 waves][SPW samples][64]
  if (li == 0) {
#pragma unroll
    for (int s = 0; s < SPW; ++s)
#pragma unroll
      for (int mi = 0; mi < 4; ++mi)
#pragma unroll
        for (int r = 0; r < 4; ++r)
          hs[(wv * SPW + s) * 64 + 16 * mi + 4 * g + r] = h[s][mi][r];
  }
  __syncthreads();
  if (lane < 10 * SPW) {
    int smp = lane / 10, c = lane % 10;
    float acc = bc[c];
    const float* hrow = hs + (wv * SPW + smp) * 64;
    for (int d = 0; d < DM; ++d) acc += hrow[d] * Wc[d * NOUT + c];
    out[(size_t)(s0 + smp) * NOUT + c] = acc;
  }
}

extern "C" void kernel_launch(void* const* d_in, const int* in_sizes, int n_in,
                              void* d_out, int out_size, void* d_ws, size_t ws_size,
                              hipStream_t stream) {
  const float* x = (const float*)d_in[0];
  const float* Wq = (const float*)d_in[2];
  const float* bq = (const float*)d_in[3];
  const float* Wk = (const float*)d_in[4];
  const float* bk = (const float*)d_in[5];
  const float* Wv = (const float*)d_in[6];
  const float* bv = (const float*)d_in[7];
  const float* Wo = (const float*)d_in[8];
  const float* bo = (const float*)d_in[9];
  const float* Wcat = (const float*)d_in[10];
  const float* bcat = (const float*)d_in[11];
  const float* ln1_g = (const float*)d_in[12];
  const float* ln1_b = (const float*)d_in[13];
  const float* ln2_g = (const float*)d_in[14];
  const float* ln2_b = (const float*)d_in[15];
  const float* W1 = (const float*)d_in[16];
  const float* b1 = (const float*)d_in[17];
  const float* W2 = (const float*)d_in[18];
  const float* b2 = (const float*)d_in[19];
  const float* Wc = (const float*)d_in[20];
  const float* bc = (const float*)d_in[21];

  unsigned short* blob = (unsigned short*)d_ws;  // NWIN * 8192 ushorts
  float* Cscr = (float*)(blob + (size_t)NWIN * 8192);  // 72 * 3200 f32
  float* fp = Cscr + (size_t)72 * 3200;
  float* g1p = fp;
  float* b1p = g1p + 384;
  float* g2p = b1p + 384;
  float* b2lp = g2p + 384;
  float* b2p = b2lp + 384;

  prep_g_frag<<<72, 256, 0, stream>>>(Wq, bq, Wk, bk, blob);
  prep_comb_f32<<<72, 256, 0, stream>>>(Wo, bo, Wcat, bcat, Cscr);
  prep_vc_frag<<<72, 256, 0, stream>>>(Wv, bv, Cscr, blob);
  prep_ff_frag<<<48, 256, 0, stream>>>(W1, b1, W2, blob);
  prep_small<<<1, 384, 0, stream>>>(ln1_g, ln1_b, ln2_g, ln2_b, b2, g1p, b1p, g2p, b2lp, b2p);

  transformer_kernel<<<NB / 8, 256, 0, stream>>>(
      x, (float*)d_out, blob, g1p, b1p, g2p, b2lp, b2p, Wc, bc);
}

// Round 20
// 525.755 us; speedup vs baseline: 1.3311x; 1.0013x over previous
//
#include <hip/hip_runtime.h>
#include <hip/hip_bf16.h>

#define LYR 6
#define NH 12
#define DM 49
#define FFD 1024
#define NOUT 10
#define NB 8192
#define NWIN 174  // per layer: 12 attn + 17 skewed ff windows (16 KB each)
#define SPW 2     // samples per wave

typedef __bf16 bf16x8 __attribute__((ext_vector_type(8)));
typedef float f32x4 __attribute__((ext_vector_type(4)));
typedef unsigned int u32;
typedef u32 u32x4 __attribute__((ext_vector_type(4)));

static __device__ __forceinline__ f32x4 mfma_full(u32x4 a, u32x4 b, f32x4 c) {
  return __builtin_amdgcn_mfma_f32_16x16x32_bf16(
      __builtin_bit_cast(bf16x8, a), __builtin_bit_cast(bf16x8, b), c, 0, 0, 0);
}

static __device__ __forceinline__ f32x4 mfma_hz(u32 a0, u32 a1, u32 b0, u32 b1, f32x4 c) {
  u32x4 A = {a0, a1, 0u, 0u};
  u32x4 B = {b0, b1, 0u, 0u};
  return mfma_full(A, B, c);
}

static __device__ __forceinline__ unsigned short f2bf(float f) {
  union { float f; unsigned u; } c; c.f = f;
  unsigned r = c.u + 0x7fffu + ((c.u >> 16) & 1u);
  return (unsigned short)(r >> 16);
}

// packed f32x2 -> bf16x2 ; lowers to v_cvt_pk_bf16_f32 (RNE, same as f2bf)
static __device__ __forceinline__ u32 pk2(float a, float b) {
  __hip_bfloat162 h2 = __float22bfloat162_rn(make_float2(a, b));
  u32 r;
  __builtin_memcpy(&r, &h2, 4);
  return r;
}

// direct global->LDS copy, 16B per lane; lds dest must be wave-uniform base
static __device__ __forceinline__ void gload16(const void* gp, void* lp) {
  __builtin_amdgcn_global_load_lds(
      (const __attribute__((address_space(1))) unsigned int*)gp,
      (__attribute__((address_space(3))) unsigned int*)lp, 16, 0, 0);
}

// ============ fragment-linear section decode ============
// section = 4096 ushorts: idx = ((tile*2+ks)*64+lane)*8 + j
// col = 16*tile + (lane&15);  k-slot d = 16*(2*ks + (j>=4)) + 4*(lane>>4) + (j&3)
static __device__ __forceinline__ void decode(int idx, int& d, int& col) {
  int tile = idx >> 10, ks = (idx >> 9) & 1, lane = (idx >> 3) & 63, j = idx & 7;
  col = 16 * tile + (lane & 15);
  d = 16 * (2 * ks + (j >= 4 ? 1 : 0)) + 4 * (lane >> 4) + (j & 3);
}

// blob layout: 174 x 16KB windows. Per layer l (29 windows at l*29):
//   pair p (heads 2p,2p+1): w=l*29+2p: [G_{2p}|G_{2p+1}]  w+1: [VC_{2p}|VC_{2p+1}]
//   ff (skewed): window l*29+12+k = [W1F_k | W2F_{k-1}], k=0..16

// G = Wk_aug @ Wq_aug^T (scores = xn^T G xn), bias rows folded, QS folded.
__global__ void prep_g_frag(const float* __restrict__ Wq, const float* __restrict__ bq,
                            const float* __restrict__ Wk, const float* __restrict__ bk,
                            unsigned short* __restrict__ blob) {
  const float QS = 1.44269504088896f / 7.0f;  // log2e/sqrt(D): softmax uses exp2
  int lh = blockIdx.x, l = lh / NH, hd = lh % NH;
  unsigned short* base =
      blob + (size_t)(l * 29 + 2 * (hd >> 1)) * 8192 + (hd & 1) * 4096;
  for (int idx = threadIdx.x; idx < 4096; idx += blockDim.x) {
    int kk, cc;
    decode(idx, kk, cc);
    float acc = 0.f;
    if (cc <= DM && kk <= DM) {
      for (int e = 0; e < DM; ++e) {
        float kv = (cc < DM) ? Wk[(size_t)lh * 2401 + cc * DM + e] : bk[lh * DM + e];
        float qv = (kk < DM) ? Wq[(size_t)lh * 2401 + kk * DM + e] : bq[lh * DM + e];
        acc += kv * qv;
      }
      acc *= QS;
    }
    base[idx] = f2bf(acc);
  }
}

// Wcomb_aug (f32 scratch): C[lh][e][f], e in [0,49] (e=DM row = bias row), f in [0,64)
__global__ void prep_comb_f32(const float* __restrict__ Wo, const float* __restrict__ bo,
                              const float* __restrict__ Wcat, const float* __restrict__ bcat,
                              float* __restrict__ C) {
  int lh = blockIdx.x, l = lh / NH, hh = lh % NH;
  float* base = C + (size_t)lh * 3200;  // [50][64]
  for (int idx = threadIdx.x; idx < 3200; idx += blockDim.x) {
    int e = idx >> 6, f = idx & 63;
    float val = 0.f;
    if (f < DM) {
      if (e < DM) {
        for (int c = 0; c < DM; ++c)
          val += Wo[(size_t)lh * 2401 + e * DM + c] *
                 Wcat[((size_t)l * 588 + hh * DM + c) * DM + f];
      } else {  // e == DM: bias row from bo (+ bcat once, head 0)
        for (int c = 0; c < DM; ++c)
          val += bo[lh * DM + c] * Wcat[((size_t)l * 588 + hh * DM + c) * DM + f];
        if (hh == 0) val += bcat[l * DM + f];
      }
    }
    base[idx] = val;
  }
}

// W_vc = Wv_aug @ Wcomb[:DM]  (+ Wcomb bias row folded into d=DM, since sum(p)=1)
__global__ void prep_vc_frag(const float* __restrict__ Wv, const float* __restrict__ bv,
                             const float* __restrict__ C,
                             unsigned short* __restrict__ blob) {
  int lh = blockIdx.x, l = lh / NH, hd = lh % NH;
  const float* Cb = C + (size_t)lh * 3200;
  unsigned short* base =
      blob + (size_t)(l * 29 + 2 * (hd >> 1) + 1) * 8192 + (hd & 1) * 4096;
  for (int idx = threadIdx.x; idx < 4096; idx += blockDim.x) {
    int d, f;
    decode(idx, d, f);
    float acc = 0.f;
    if (f < DM && d <= DM) {
      for (int e = 0; e < DM; ++e) {
        float wv = (d < DM) ? Wv[(size_t)lh * 2401 + d * DM + e] : bv[lh * DM + e];
        acc += wv * Cb[e * 64 + f];
      }
      if (d == DM) acc += Cb[DM * 64 + f];  // comb bias row (softmax rows sum to 1)
    }
    base[idx] = f2bf(acc);
  }
}

// Skewed FF: W1F_c -> window (12+c) first half; W2F_c -> window (12+c+1) second half
__global__ void prep_ff_frag(const float* __restrict__ W1, const float* __restrict__ b1,
                             const float* __restrict__ W2,
                             unsigned short* __restrict__ blob) {
  int l = blockIdx.x >> 3, part = blockIdx.x & 7;
  for (int idx = part * 16384 + threadIdx.x; idx < (part + 1) * 16384; idx += blockDim.x) {
    int c = idx >> 13, within = idx & 8191, sec = within >> 12, sidx = within & 4095;
    unsigned short* dst =
        blob + (size_t)(l * 29 + 12 + c + sec) * 8192 + sec * 4096;
    int d, col;
    decode(sidx, d, col);
    float v = 0.f;
    if (sec == 0) {  // W1: cols j, k = d_aug
      int jcol = 64 * c + col;
      if (d < DM) v = W1[(size_t)l * DM * FFD + d * FFD + jcol];
      else if (d == DM) v = b1[l * FFD + jcol];
    } else {  // W2: cols f, k = j within chunk
      int jg = 64 * c + d;
      if (col < DM) v = W2[(size_t)l * FFD * DM + jg * DM + col];
    }
    dst[sidx] = f2bf(v);
  }
}

__global__ void prep_small(const float* __restrict__ g1, const float* __restrict__ b1,
                           const float* __restrict__ g2, const float* __restrict__ b2,
                           const float* __restrict__ bff2,
                           float* __restrict__ g1p, float* __restrict__ b1p,
                           float* __restrict__ g2p, float* __restrict__ b2p,
                           float* __restrict__ bff2p) {
  int idx = threadIdx.x;
  if (idx >= 384) return;
  int l = idx >> 6, d = idx & 63;
  bool v = d < DM;
  g1p[idx] = v ? g1[l * DM + d] : 0.f;
  b1p[idx] = v ? b1[l * DM + d] : 0.f;
  g2p[idx] = v ? g2[l * DM + d] : 0.f;
  b2p[idx] = v ? b2[l * DM + d] : 0.f;
  bff2p[idx] = v ? bff2[l * DM + d] : 0.f;
}

// ===== fused transformer: SPW=2, 4-wave blocks, 4 blocks/CU, skewed FF pipeline =====

static __device__ __forceinline__ void ln_pack(const f32x4 (&h)[4], const f32x4 (&gv)[4],
                                               const f32x4 (&bv)[4], int g, u32x4 (&xf)[2]) {
  float s = 0.f, s2 = 0.f;
#pragma unroll
  for (int mi = 0; mi < 4; ++mi)
#pragma unroll
    for (int r = 0; r < 4; ++r) { float v = h[mi][r]; s += v; s2 += v * v; }
  s += __shfl_xor(s, 16, 64); s += __shfl_xor(s, 32, 64);
  s2 += __shfl_xor(s2, 16, 64); s2 += __shfl_xor(s2, 32, 64);
  float mu = s * (1.f / 49.f);
  float rs = rsqrtf(s2 * (1.f / 49.f) - mu * mu + 1e-5f);
  u32 t[8];
#pragma unroll
  for (int mi = 0; mi < 4; ++mi) {
    float xv[4];
#pragma unroll
    for (int r = 0; r < 4; ++r) xv[r] = (h[mi][r] - mu) * rs * gv[mi][r] + bv[mi][r];
    if (mi == 3) xv[1] = (g == 0) ? 1.0f : xv[1];  // bias slot d=49 := 1
    t[2 * mi] = pk2(xv[0], xv[1]);
    t[2 * mi + 1] = pk2(xv[2], xv[3]);
  }
  xf[0] = u32x4{t[0], t[1], t[2], t[3]};
  xf[1] = u32x4{t[4], t[5], t[6], t[7]};
}

// scores are O(1) (0.02-std weights, LN'd acts); log2e pre-folded -> plain exp2
static __device__ __forceinline__ void softmax_pk(f32x4 s, u32& p0, u32& p1) {
  float e0 = exp2f(s[0]), e1 = exp2f(s[1]);
  float e2 = exp2f(s[2]), e3 = exp2f(s[3]);
  float su = e0 + e1 + e2 + e3;
  su += __shfl_xor(su, 16, 64);
  su += __shfl_xor(su, 32, 64);
  float inv = 1.f / su;
  p0 = pk2(e0 * inv, e1 * inv);
  p1 = pk2(e2 * inv, e3 * inv);
}

// issue next window's loads: per-lane global src, wave-uniform LDS dest + lane*16
// 4 waves x 4 instrs x 512 ushorts = 8192 ushort window
#define STAGE_LOAD(s)                                                         \
  do {                                                                        \
    const unsigned short* gsrc = blob + (size_t)(s) * 8192 + tid * 8;         \
    unsigned short* ldst = &wbuf[(s) & 1][wv * 512];                          \
    _Pragma("unroll") for (int r = 0; r < 4; ++r)                             \
        gload16(gsrc + r * 2048, ldst + r * 2048);                            \
  } while (0)

__global__ __launch_bounds__(256, 4) void transformer_kernel(
    const float* __restrict__ x, float* __restrict__ out,
    const unsigned short* __restrict__ blob,
    const float* __restrict__ lg1, const float* __restrict__ lb1,
    const float* __restrict__ lg2, const float* __restrict__ lb2,
    const float* __restrict__ b2p, const float* __restrict__ Wc,
    const float* __restrict__ bc) {
  __shared__ __align__(16) unsigned short wbuf[2][8192];
  const int tid = threadIdx.x;
  const int wv = tid >> 6, lane = tid & 63;
  const int g = lane >> 4, li = lane & 15;
  const int s0 = blockIdx.x * 8 + wv * 2;
  const f32x4 z4 = {0.f, 0.f, 0.f, 0.f};

  STAGE_LOAD(0);

  // h tiles: h[s][mi][r] = h[d=16mi+4g+r][t=li] for sample s0+s
  f32x4 h[SPW][4];
#pragma unroll
  for (int s = 0; s < SPW; ++s) {
    const float* xa = x + (size_t)(s0 + s) * 784 + li * DM;
#pragma unroll
    for (int mi = 0; mi < 4; ++mi)
#pragma unroll
      for (int r = 0; r < 4; ++r) {
        int d = 16 * mi + 4 * g + r;
        h[s][mi][r] = (d < DM) ? xa[d] : 0.f;
      }
  }

  int w = 0;
  for (int layer = 0; layer < LYR; ++layer) {
    u32x4 xf[SPW][2];
    {
      f32x4 gv[4], bv[4];
#pragma unroll
      for (int mi = 0; mi < 4; ++mi) {
        int off = layer * 64 + 16 * mi + 4 * g;
        gv[mi] = *(const f32x4*)(lg1 + off);
        bv[mi] = *(const f32x4*)(lb1 + off);
      }
#pragma unroll
      for (int s = 0; s < SPW; ++s) ln_pack(h[s], gv, bv, g, xf[s]);
    }

    for (int hp = 0; hp < 6; ++hp) {
      // ---- window [G0|G1]: y = G @ xn, scores (per head, sequential) ----
      __syncthreads();
      STAGE_LOAD(w + 1);
      f32x4 sc[2][SPW];  // carried across the next barrier
#pragma unroll
      for (int hh = 0; hh < 2; ++hh) {
        const u32x4* GW = (const u32x4*)(wbuf[w & 1] + hh * 4096);
        __builtin_amdgcn_s_setprio(1);
        u32x4 yf[SPW][2];
#pragma unroll
        for (int mi = 0; mi < 4; ++mi) {
          f32x4 cy[SPW];
#pragma unroll
          for (int s = 0; s < SPW; ++s) cy[s] = z4;
#pragma unroll
          for (int ks = 0; ks < 2; ++ks) {
            u32x4 gw = GW[(mi * 2 + ks) * 64 + lane];
#pragma unroll
            for (int s = 0; s < SPW; ++s) cy[s] = mfma_full(gw, xf[s][ks], cy[s]);
          }
#pragma unroll
          for (int s = 0; s < SPW; ++s) {
            yf[s][mi >> 1][2 * (mi & 1)] = pk2(cy[s][0], cy[s][1]);
            yf[s][mi >> 1][2 * (mi & 1) + 1] = pk2(cy[s][2], cy[s][3]);
          }
        }
#pragma unroll
        for (int s = 0; s < SPW; ++s) {
          sc[hh][s] = mfma_full(xf[s][0], yf[s][0], z4);
          sc[hh][s] = mfma_full(xf[s][1], yf[s][1], sc[hh][s]);
        }
        __builtin_amdgcn_s_setprio(0);
      }
      ++w;

      // ---- window [VC0|VC1]: u = xn @ Wvc ; softmax (overlapped) ; h += p @ u ----
      __syncthreads();
      STAGE_LOAD(w + 1);
#pragma unroll
      for (int hh = 0; hh < 2; ++hh) {
        const u32x4* UW = (const u32x4*)(wbuf[w & 1] + hh * 4096);
        __builtin_amdgcn_s_setprio(1);
        u32 uf[4][SPW][2];
#pragma unroll
        for (int nt = 0; nt < 4; ++nt) {
          f32x4 cu[SPW];
#pragma unroll
          for (int s = 0; s < SPW; ++s) cu[s] = z4;
#pragma unroll
          for (int ks = 0; ks < 2; ++ks) {
            u32x4 wu = UW[(nt * 2 + ks) * 64 + lane];
#pragma unroll
            for (int s = 0; s < SPW; ++s) cu[s] = mfma_full(xf[s][ks], wu, cu[s]);
          }
#pragma unroll
          for (int s = 0; s < SPW; ++s) {
            uf[nt][s][0] = pk2(cu[s][0], cu[s][1]);
            uf[nt][s][1] = pk2(cu[s][2], cu[s][3]);
          }
        }
        // softmax here: VALU chain independent of the u MFMAs above -> overlaps
        u32 p[SPW][2];
#pragma unroll
        for (int s = 0; s < SPW; ++s) softmax_pk(sc[hh][s], p[s][0], p[s][1]);
        // PV (K=16) directly into the residual h
#pragma unroll
        for (int nt = 0; nt < 4; ++nt)
#pragma unroll
          for (int s = 0; s < SPW; ++s)
            h[s][nt] = mfma_hz(uf[nt][s][0], uf[nt][s][1], p[s][0], p[s][1], h[s][nt]);
        __builtin_amdgcn_s_setprio(0);
      }
      ++w;
    }

    // LN2 on x2 (= h), then h += b2 so FF2 accumulates into the residual
    {
      f32x4 gv[4], bv[4];
#pragma unroll
      for (int mi = 0; mi < 4; ++mi) {
        int off = layer * 64 + 16 * mi + 4 * g;
        gv[mi] = *(const f32x4*)(lg2 + off);
        bv[mi] = *(const f32x4*)(lb2 + off);
      }
#pragma unroll
      for (int s = 0; s < SPW; ++s) ln_pack(h[s], gv, bv, g, xf[s]);
#pragma unroll
      for (int mi = 0; mi < 4; ++mi) {
        f32x4 bb = *(const f32x4*)(b2p + layer * 64 + 16 * mi + 4 * g);
#pragma unroll
        for (int s = 0; s < SPW; ++s) h[s][mi] += bb;
      }
    }

    // ---- skewed FF: window k = [W1_k | W2_{k-1}]; FF2(k-1) || FF1(k) ----
    u32x4 af[SPW][2];
    {  // k = 0: FF1(0) only
      __syncthreads();
      STAGE_LOAD(w + 1);
      const u32x4* W1c = (const u32x4*)wbuf[w & 1];
      __builtin_amdgcn_s_setprio(1);
#pragma unroll
      for (int jt = 0; jt < 4; ++jt) {
        f32x4 ca[SPW];
#pragma unroll
        for (int s = 0; s < SPW; ++s) ca[s] = z4;
#pragma unroll
        for (int ks = 0; ks < 2; ++ks) {
          u32x4 ww = W1c[(jt * 2 + ks) * 64 + lane];
#pragma unroll
          for (int s = 0; s < SPW; ++s) ca[s] = mfma_full(ww, xf[s][ks], ca[s]);
        }
#pragma unroll
        for (int s = 0; s < SPW; ++s) {
          af[s][jt >> 1][2 * (jt & 1)] = pk2(fmaxf(ca[s][0], 0.f), fmaxf(ca[s][1], 0.f));
          af[s][jt >> 1][2 * (jt & 1) + 1] = pk2(fmaxf(ca[s][2], 0.f), fmaxf(ca[s][3], 0.f));
        }
      }
      __builtin_amdgcn_s_setprio(0);
      ++w;
    }
    for (int k = 1; k < 16; ++k) {
      __syncthreads();
      STAGE_LOAD(w + 1);
      const u32x4* W1c = (const u32x4*)wbuf[w & 1];
      const u32x4* W2c = (const u32x4*)(wbuf[w & 1] + 4096);
      __builtin_amdgcn_s_setprio(1);
      // FF2(k-1): uses af from the previous window — independent of FF1(k)
#pragma unroll
      for (int ft = 0; ft < 4; ++ft)
#pragma unroll
        for (int ks = 0; ks < 2; ++ks) {
          u32x4 ww = W2c[(ft * 2 + ks) * 64 + lane];
#pragma unroll
          for (int s = 0; s < SPW; ++s) h[s][ft] = mfma_full(ww, af[s][ks], h[s][ft]);
        }
      // FF1(k) -> af (overwritten after FF2 consumed it)
#pragma unroll
      for (int jt = 0; jt < 4; ++jt) {
        f32x4 ca[SPW];
#pragma unroll
        for (int s = 0; s < SPW; ++s) ca[s] = z4;
#pragma unroll
        for (int ks = 0; ks < 2; ++ks) {
          u32x4 ww = W1c[(jt * 2 + ks) * 64 + lane];
#pragma unroll
          for (int s = 0; s < SPW; ++s) ca[s] = mfma_full(ww, xf[s][ks], ca[s]);
        }
#pragma unroll
        for (int s = 0; s < SPW; ++s) {
          af[s][jt >> 1][2 * (jt & 1)] = pk2(fmaxf(ca[s][0], 0.f), fmaxf(ca[s][1], 0.f));
          af[s][jt >> 1][2 * (jt & 1) + 1] = pk2(fmaxf(ca[s][2], 0.f), fmaxf(ca[s][3], 0.f));
        }
      }
      __builtin_amdgcn_s_setprio(0);
      ++w;
    }
    {  // k = 16: FF2(15) only
      __syncthreads();
      if (w + 1 < NWIN) STAGE_LOAD(w + 1);
      const u32x4* W2c = (const u32x4*)(wbuf[w & 1] + 4096);
      __builtin_amdgcn_s_setprio(1);
#pragma unroll
      for (int ft = 0; ft < 4; ++ft)
#pragma unroll
        for (int ks = 0; ks < 2; ++ks) {
          u32x4 ww = W2c[(ft * 2 + ks) * 64 + lane];
#pragma unroll
          for (int s = 0; s < SPW; ++s) h[s][ft] = mfma_full(ww, af[s][ks], h[s][ft]);
        }
      __builtin_amdgcn_s_setprio(0);
      ++w;
    }
  }

  // ---- classification head on token 0 (col li==0); overlay scratch on wbuf ----
  __syncthreads();
  float* hs = (float*)&wbuf[0][0];  // [4 waves][SPW samples][64]
  if (li == 0) {
#pragma unroll
    for (int s = 0; s < SPW; ++s)
#pragma unroll
      for (int mi = 0; mi < 4; ++mi)
#pragma unroll
        for (int r = 0; r < 4; ++r)
          hs[(wv * SPW + s) * 64 + 16 * mi + 4 * g + r] = h[s][mi][r];
  }
  __syncthreads();
  if (lane < 10 * SPW) {
    int smp = lane / 10, c = lane % 10;
    float acc = bc[c];
    const float* hrow = hs + (wv * SPW + smp) * 64;
    for (int d = 0; d < DM; ++d) acc += hrow[d] * Wc[d * NOUT + c];
    out[(size_t)(s0 + smp) * NOUT + c] = acc;
  }
}

extern "C" void kernel_launch(void* const* d_in, const int* in_sizes, int n_in,
                              void* d_out, int out_size, void* d_ws, size_t ws_size,
                              hipStream_t stream) {
  const float* x = (const float*)d_in[0];
  const float* Wq = (const float*)d_in[2];
  const float* bq = (const float*)d_in[3];
  const float* Wk = (const float*)d_in[4];
  const float* bk = (const float*)d_in[5];
  const float* Wv = (const float*)d_in[6];
  const float* bv = (const float*)d_in[7];
  const float* Wo = (const float*)d_in[8];
  const float* bo = (const float*)d_in[9];
  const float* Wcat = (const float*)d_in[10];
  const float* bcat = (const float*)d_in[11];
  const float* ln1_g = (const float*)d_in[12];
  const float* ln1_b = (const float*)d_in[13];
  const float* ln2_g = (const float*)d_in[14];
  const float* ln2_b = (const float*)d_in[15];
  const float* W1 = (const float*)d_in[16];
  const float* b1 = (const float*)d_in[17];
  const float* W2 = (const float*)d_in[18];
  const float* b2 = (const float*)d_in[19];
  const float* Wc = (const float*)d_in[20];
  const float* bc = (const float*)d_in[21];

  unsigned short* blob = (unsigned short*)d_ws;  // NWIN * 8192 ushorts
  float* Cscr = (float*)(blob + (size_t)NWIN * 8192);  // 72 * 3200 f32
  float* fp = Cscr + (size_t)72 * 3200;
  float* g1p = fp;
  float* b1p = g1p + 384;
  float* g2p = b1p + 384;
  float* b2lp = g2p + 384;
  float* b2p = b2lp + 384;

  prep_g_frag<<<72, 256, 0, stream>>>(Wq, bq, Wk, bk, blob);
  prep_comb_f32<<<72, 256, 0, stream>>>(Wo, bo, Wcat, bcat, Cscr);
  prep_vc_frag<<<72, 256, 0, stream>>>(Wv, bv, Cscr, blob);
  prep_ff_frag<<<48, 256, 0, stream>>>(W1, b1, W2, blob);
  prep_small<<<1, 384, 0, stream>>>(ln1_g, ln1_b, ln2_g, ln2_b, b2, g1p, b1p, g2p, b2lp, b2p);

  transformer_kernel<<<NB / 8, 256, 0, stream>>>(
      x, (float*)d_out, blob, g1p, b1p, g2p, b2lp, b2p, Wc, bc);
}